// Round 2
// 334.982 us; speedup vs baseline: 1.8388x; 1.8388x over previous
//
#include <hip/hip_runtime.h>

// r16: f16 MFMA conv with EXACT (fp32-grade) numerics via hi/lo split.
// r15's pred failure diagnosed as f16 quantization flipping argmax on
// near-tied logit rows. Now x and w are each split into hi+lo f16 pairs;
// conv computes x_hi*w_hi + x_lo*w_hi + x_hi*w_lo (3 MFMA segments,
// error ~2^-22). Weights pre-scaled x64 so w_lo is f16-normal; epilogue
// divides by 64. Weight tensors are pre-split/transposed/bank-swizzled
// once into workspace [tensor][tap][co][16 chunks^(co&7)][8] f16, so conv
// staging is a linear global->reg->LDS copy and B-fragment ds_read_b128
// is bank-uniform. gates/LN/LSTM/head stay fp32 (head reconstructs
// h = hi+lo exactly). Workspace 14.75 MiB (17.8 MiB ran fine in r15).

typedef _Float16 f16;
typedef _Float16 f16x8 __attribute__((ext_vector_type(8)));
typedef float    f32x4 __attribute__((ext_vector_type(4)));

#define WSTRIDE 442368   // fp32 weight elements per layer: 27*64*256
#define WPT     884736   // halfs per split tensor: 27*256*128
#define XSP     65536    // halfs per s-slab of h: 512*128
#define HSP     458752   // halfs per nc of h: 7*512*128

__device__ __forceinline__ float wred_sum(float v) {
    #pragma unroll
    for (int o = 32; o > 0; o >>= 1) v += __shfl_down(v, o, 64);
    return __shfl(v, 0, 64);
}
__device__ __forceinline__ float fsig(float x)  { return 1.f / (1.f + __expf(-x)); }
__device__ __forceinline__ float ftanh(float x) { return 1.f - 2.f / (__expf(2.f*x) + 1.f); }

// h[nc][s][vox][128] = hi/lo split of emb[tok][ch]
__global__ __launch_bounds__(256) void embed_kernel(
    const int* __restrict__ code, const int* __restrict__ ncode,
    const float* __restrict__ emb, f16* __restrict__ h)
{
    int e = blockIdx.x * 256 + threadIdx.x;   // < 458752
    int ch = e & 63;
    int pos = e >> 6;            // nc*7*512 + s*512 + vox
    int vox = pos & 511;
    int t = pos >> 9;
    int s = t % 7, nc = t / 7;
    int tok = (s < 5) ? code[(nc*5 + s)*512 + vox]
                      : ncode[(nc*3 + (s-5))*512 + vox];
    float x = emb[tok*64 + ch];
    f16 hi = (f16)x;
    h[(size_t)pos*128 + ch]      = hi;
    h[(size_t)pos*128 + 64 + ch] = (f16)(x - (float)hi);
}

// Split+transpose+swizzle weights: src [27][64 ci][256 co] fp32 ->
// dst [27][256 co][16 chunks][8] f16 where chunk (ci>>3) of hi goes to
// slot (ci>>3)^(co&7) and lo to that +8. Values scaled x64.
// Tensor order: win[0], wh[0], win[1], wh[1].
__global__ __launch_bounds__(256) void wsplit_kernel(
    const float* __restrict__ win, const float* __restrict__ wh,
    f16* __restrict__ wp)
{
    int b = blockIdx.x;               // 108 = 4 tensors * 27 taps
    int tensor = b / 27, tap = b % 27;
    const float* src = ((tensor & 1) ? wh : win) + (tensor >> 1) * WSTRIDE
                     + tap * 16384;
    int co = threadIdx.x;
    int sw = co & 7;
    f16* dst = wp + ((size_t)(tensor*27 + tap)*256 + co) * 128;
    #pragma unroll
    for (int c8 = 0; c8 < 8; ++c8) {
        f16x8 hi8, lo8;
        #pragma unroll
        for (int j = 0; j < 8; ++j) {
            float w = src[(c8*8 + j)*256 + co] * 64.f;
            f16 hv = (f16)w;
            hi8[j] = hv;
            lo8[j] = (f16)(w - (float)hv);
        }
        *(f16x8*)(dst + ((c8 ^ sw)    )*8) = hi8;
        *(f16x8*)(dst + ((c8 ^ sw) + 8)*8) = lo8;
    }
}

struct MJob { const f16* x; const f16* w; const float* bias; float* y; };
struct MJobs { MJob j[4]; };

// One 3x3x3 SAME conv job (Cin=64 -> Cout=256), implicit GEMM via
// mfma_f32_16x16x32_f16 with 3-segment hi/lo split (fp32-exact).
// grid.x = 64 per job: slab(2) x u(8) x cog(4). 4 waves K-split by taps
// (7/7/7/6), each staging its tap's [64co][128] w-tile into a private
// 16KB LDS region (single-buffered; per-wave LDS is in-order). A-frags
// read straight from global with halo predication. One barrier total;
// 4-way K-reduce through the same 64KB LDS.
__global__ __launch_bounds__(256, 1) void conv_mfma_kernel(MJobs js)
{
    const MJob J = js.j[blockIdx.y];
    __shared__ float4 smem[4096];          // 64 KiB
    f16* wbuf = (f16*)smem;

    const int bx = blockIdx.x;
    const int slab = bx >> 5, u = (bx >> 2) & 7, cog = bx & 3;
    const int t = threadIdx.x, wid = t >> 6, l = t & 63;
    const int lv = (l >> 3) & 1, lw = l & 7, khi = l >> 4;

    const f16* xbase = J.x + (size_t)slab * HSP;
    const f16* wjob  = J.w + (size_t)cog * 8192;      // + tap*32768
    f16* wmine = wbuf + wid * 8192;                   // [64co][16ch][8]

    const int t0 = wid * 7;
    const int ntap = (wid == 3) ? 6 : 7;

    f16x8 wreg[16];
    auto wload = [&](int tap) {           // global -> regs (linear, coalesced)
        const f16* src = wjob + (size_t)tap * 32768 + l * 8;
        #pragma unroll
        for (int i = 0; i < 16; ++i) wreg[i] = *(const f16x8*)(src + i * 512);
    };
    auto wstore = [&]() {                 // regs -> LDS (linear)
        f16* dst = wmine + l * 8;
        #pragma unroll
        for (int i = 0; i < 16; ++i) *(f16x8*)(dst + i * 512) = wreg[i];
    };

    wload(t0); wstore();

    f32x4 acc[4][4] = {};                 // [a: vox 16-tile][n: co 16-tile]
    for (int tt = 0; tt < ntap; ++tt) {
        const int tap = t0 + tt;
        if (tt + 1 < ntap) wload(tap + 1);          // prefetch next tap
        const int du = tap / 9, rr = tap % 9, dv = rr / 3, dw = rr % 3;
        const int uu = u + du - 1;
        const bool uok = (unsigned)uu < 8u;
        const f16* xrow[4]; bool ok[4];
        #pragma unroll
        for (int a = 0; a < 4; ++a) {               // vox = a*16 + (l&15)
            int vs = a*2 + lv + dv - 1, ws = lw + dw - 1;
            ok[a] = uok && (unsigned)vs < 8u && (unsigned)ws < 8u;
            xrow[a] = xbase + ((size_t)(uu*64 + vs*8 + ws) << 7) + khi*8;
        }
        const f16* wrow = wmine + (l & 15) * 128;
        #pragma unroll
        for (int hs = 0; hs < 2; ++hs) {
            const int sc = ((hs*4 + khi) ^ lw) * 8;   // lw == co_local&7
            f16x8 ahi[4], alo[4], bhi[4], blo[4];
            #pragma unroll
            for (int a = 0; a < 4; ++a) {
                f16x8 v = {0,0,0,0,0,0,0,0}, v2 = v;
                if (ok[a]) {
                    v  = *(const f16x8*)(xrow[a] + hs*32);
                    v2 = *(const f16x8*)(xrow[a] + 64 + hs*32);
                }
                ahi[a] = v; alo[a] = v2;
            }
            #pragma unroll
            for (int n = 0; n < 4; ++n) {
                bhi[n] = *(const f16x8*)(wrow + n*2048 + sc);
                blo[n] = *(const f16x8*)(wrow + n*2048 + 64 + sc);
            }
            #pragma unroll
            for (int a = 0; a < 4; ++a)
                #pragma unroll
                for (int n = 0; n < 4; ++n)
                    acc[a][n] = __builtin_amdgcn_mfma_f32_16x16x32_f16(
                        ahi[a], bhi[n], acc[a][n], 0, 0, 0);
            #pragma unroll
            for (int a = 0; a < 4; ++a)
                #pragma unroll
                for (int n = 0; n < 4; ++n)
                    acc[a][n] = __builtin_amdgcn_mfma_f32_16x16x32_f16(
                        alo[a], bhi[n], acc[a][n], 0, 0, 0);
            #pragma unroll
            for (int a = 0; a < 4; ++a)
                #pragma unroll
                for (int n = 0; n < 4; ++n)
                    acc[a][n] = __builtin_amdgcn_mfma_f32_16x16x32_f16(
                        ahi[a], blo[n], acc[a][n], 0, 0, 0);
        }
        if (tt + 1 < ntap) wstore();
    }

    // 4-way K-reduction: each wave dumps over its OWN wbuf region, then all
    // threads re-read across waves. Chunk index XORed by l&15 (bank spread).
    f32x4* red = (f32x4*)smem;
    {
        f32x4* mine = red + (size_t)(wid * 64 + l) * 16;
        #pragma unroll
        for (int a = 0; a < 4; ++a)
            #pragma unroll
            for (int n = 0; n < 4; ++n)
                mine[(a * 4 + n) ^ (l & 15)] = acc[a][n];
    }
    __syncthreads();
    {
        const int a = t >> 6, ll = t & 63;
        #pragma unroll
        for (int n = 0; n < 4; ++n) {
            const int ch = (a * 4 + n) ^ (ll & 15);
            f32x4 sv = red[(0 * 64 + ll) * 16 + ch]
                     + red[(1 * 64 + ll) * 16 + ch]
                     + red[(2 * 64 + ll) * 16 + ch]
                     + red[(3 * 64 + ll) * 16 + ch];
            const int co = cog * 64 + n * 16 + (ll & 15);
            const float bvv = J.bias[co];
            #pragma unroll
            for (int r = 0; r < 4; ++r) {           // D row = 4*(ll>>4)+r
                int vox = a * 16 + (ll >> 4) * 4 + r;
                J.y[(size_t)(slab * 512 + u * 64 + vox) * 256 + co]
                    = sv[r] * 0.015625f + bvv;      // /64 (w' scale)
            }
        }
    }
}

// Dual-LN LSTM cell (fp32 math). Writes h as hi/lo f16 pair.
struct GJob {
    const float* giraw; const float* ghat;
    const float* ginw; const float* ginb;
    const float* ghw;  const float* ghb;
    float* cx; f16* h16; int k; int k0;
};
__global__ __launch_bounds__(256) void gates_step_kernel(GJob ja, GJob jb)
{
    const GJob J = (blockIdx.y == 0) ? ja : jb;
    const int wid = threadIdx.x >> 6, lane = threadIdx.x & 63;
    const int row = blockIdx.x * 4 + wid;     // nc*512 + vox, < 1024
    const int nc = row >> 9, vox = row & 511;

    const float* g1 = J.giraw + (size_t)row*256;
    float a0 = g1[lane], a1 = g1[64+lane], a2 = g1[128+lane], a3 = g1[192+lane];
    float mu1 = wred_sum(a0+a1+a2+a3) * (1.f/256.f);
    float d0=a0-mu1, d1=a1-mu1, d2=a2-mu1, d3=a3-mu1;
    float v1 = wred_sum(d0*d0+d1*d1+d2*d2+d3*d3) * (1.f/256.f);
    float rs1 = rsqrtf(v1 + 1e-5f);

    const float* g2 = J.k0 ? J.ghat : J.ghat + (size_t)row*256;
    float b0 = g2[lane], b1 = g2[64+lane], b2 = g2[128+lane], b3 = g2[192+lane];
    float mu2 = wred_sum(b0+b1+b2+b3) * (1.f/256.f);
    float e0=b0-mu2, e1=b1-mu2, e2=b2-mu2, e3=b3-mu2;
    float v2 = wred_sum(e0*e0+e1*e1+e2*e2+e3*e3) * (1.f/256.f);
    float rs2 = rsqrtf(v2 + 1e-5f);

    float Ig = d0*rs1*J.ginw[lane]     + J.ginb[lane]     + e0*rs2*J.ghw[lane]     + J.ghb[lane];
    float Fg = d1*rs1*J.ginw[64+lane]  + J.ginb[64+lane]  + e1*rs2*J.ghw[64+lane]  + J.ghb[64+lane];
    float Cg = d2*rs1*J.ginw[128+lane] + J.ginb[128+lane] + e2*rs2*J.ghw[128+lane] + J.ghb[128+lane];
    float Og = d3*rs1*J.ginw[192+lane] + J.ginb[192+lane] + e3*rs2*J.ghw[192+lane] + J.ghb[192+lane];

    float c_old = J.k0 ? 0.f : J.cx[(size_t)row*64 + lane];
    float c_new = fsig(Fg)*c_old + fsig(Ig)*ftanh(Cg);
    float h_new = fsig(Og)*ftanh(c_new);
    J.cx[(size_t)row*64 + lane] = c_new;
    size_t hb = ((size_t)(nc*7 + J.k)*512 + vox)*128 + lane;
    f16 hi = (f16)h_new;
    J.h16[hb]      = hi;
    J.h16[hb + 64] = (f16)(h_new - (float)hi);
}

// Head: 4 voxels per block, one wave per voxel. Reads layer-2 h as hi/lo
// f16 and reconstructs exactly (h = hi + lo).
__global__ __launch_bounds__(256) void head_kernel(
    const f16* __restrict__ h,        // [2][7][512][128] hi/lo
    const float* __restrict__ w1, const float* __restrict__ b1,
    const float* __restrict__ lng, const float* __restrict__ lnb,
    const float* __restrict__ w2, const float* __restrict__ b2,
    const int* __restrict__ ncode,
    float* __restrict__ out)
{
    __shared__ float zv[4][64];
    __shared__ float lg[4][512];
    const int blk = blockIdx.x;               // 768 = 2n * 3sn * 128 voxgroups
    const int n = blk / 384;
    const int sn = (blk / 128) % 3;
    const int vox0 = (blk & 127) * 4;
    const int wid = threadIdx.x >> 6, lane = threadIdx.x & 63;
    const int vox = vox0 + wid;
    const int r = (n*3 + sn)*512 + vox;       // pred row
    const f16* hv = h + (size_t)((n*7 + sn + 4)*512 + vox)*128;

    float yv = b1[lane];
    for (int kk = 0; kk < 64; ++kk) {
        float hk = (float)hv[kk] + (float)hv[64 + kk];
        yv = fmaf(hk, w1[kk*64 + lane], yv);
    }
    float mu = wred_sum(yv) * (1.f/64.f);
    float d = yv - mu;
    float var = wred_sum(d*d) * (1.f/64.f);
    float ln = d * rsqrtf(var + 1e-5f) * lng[lane] + lnb[lane];
    zv[wid][lane] = 0.5f * ln * (1.f + erff(ln * 0.70710678118654752f));

    float l[8];
    #pragma unroll
    for (int j = 0; j < 8; ++j) l[j] = b2[j*64 + lane];
    for (int kk = 0; kk < 64; ++kk) {
        float zz = zv[wid][kk];
        #pragma unroll
        for (int j = 0; j < 8; ++j)
            l[j] = fmaf(zz, w2[kk*512 + j*64 + lane], l[j]);
    }
    #pragma unroll
    for (int j = 0; j < 8; ++j) lg[wid][j*64 + lane] = l[j];

    float m = l[0]; int mi = lane;
    #pragma unroll
    for (int j = 1; j < 8; ++j)
        if (l[j] > m) { m = l[j]; mi = j*64 + lane; }
    #pragma unroll
    for (int o = 32; o > 0; o >>= 1) {
        float om = __shfl_down(m, o, 64);
        int   oi = __shfl_down(mi, o, 64);
        if (om > m || (om == m && oi < mi)) { m = om; mi = oi; }
    }
    float maxv = __shfl(m, 0, 64);
    int   maxi = __shfl(mi, 0, 64);
    float es = 0.f;
    #pragma unroll
    for (int j = 0; j < 8; ++j) es += __expf(l[j] - maxv);
    float sum = wred_sum(es);
    if (lane == 0) {
        int target = ncode[(n*3 + sn)*512 + vox];
        float logp = lg[wid][target] - maxv - __logf(sum);
        atomicAdd(out + 1572864, -logp * (1.f/3072.f));
        out[1572865 + r] = (float)maxi;
    }

    __syncthreads();
    const int t = threadIdx.x;
    #pragma unroll
    for (int jj = 0; jj < 2; ++jj) {
        int co = t + jj*256;
        float4 o4 = { lg[0][co], lg[1][co], lg[2][co], lg[3][co] };
        *(float4*)(out + (size_t)((n*512 + co)*3 + sn)*512 + vox0) = o4;
    }
}

extern "C" void kernel_launch(void* const* d_in, const int* in_sizes, int n_in,
                              void* d_out, int out_size, void* d_ws, size_t ws_size,
                              hipStream_t stream) {
    (void)in_sizes; (void)n_in; (void)out_size; (void)ws_size;
    const int*   code  = (const int*)d_in[0];
    const int*   ncode = (const int*)d_in[1];
    const float* emb   = (const float*)d_in[2];
    const float* win   = (const float*)d_in[3];
    const float* bin_  = (const float*)d_in[4];
    const float* gin_w = (const float*)d_in[5];
    const float* gin_b = (const float*)d_in[6];
    const float* wh    = (const float*)d_in[7];
    const float* bh    = (const float*)d_in[8];
    const float* gh_w  = (const float*)d_in[9];
    const float* gh_b  = (const float*)d_in[10];
    const float* w1    = (const float*)d_in[11];
    const float* b1    = (const float*)d_in[12];
    const float* ln_g  = (const float*)d_in[13];
    const float* ln_b  = (const float*)d_in[14];
    const float* w2    = (const float*)d_in[15];
    const float* b2    = (const float*)d_in[16];
    float* out = (float*)d_out;

    float* base  = (float*)d_ws;
    f16*   wp    = (f16*)base;                    // 4*884736 halfs = 1,769,472 f
    f16*   h1    = (f16*)(base + 1769472);        // [2][7][512][128] hi/lo
    f16*   h2    = h1 + 917504;
    float* gi1   = base + 2686976;                // [2][512][256]
    float* gi2   = gi1 + 262144;
    float* ghat1 = gi2 + 262144;
    float* ghat2 = ghat1 + 262144;
    float* cx1   = ghat2 + 262144;                // [2][512][64]
    float* cx2   = cx1 + 65536;                   // end: 3,866,624 floats

    const f16* win0 = wp;
    const f16* wh0  = wp + WPT;
    const f16* win1 = wp + 2*WPT;
    const f16* wh1  = wp + 3*WPT;

    hipMemsetAsync(out + 1572864, 0, sizeof(float), stream);   // loss accumulator
    embed_kernel<<<1792, 256, 0, stream>>>(code, ncode, emb, h1);
    wsplit_kernel<<<108, 256, 0, stream>>>(win, wh, wp);

    // pre-loop: gi1(0) = conv(emb h1[0], win0)
    {
        MJobs js{};
        js.j[0] = { h1, win0, bin_, gi1 };
        conv_mfma_kernel<<<dim3(64, 1), 256, 0, stream>>>(js);
    }

    for (int s = 0; s <= 7; ++s) {
        // ---- gates: gates1(s) [s<=6], gates2(s-1) [s>=1] ----
        GJob g1 = { gi1, (s == 0) ? bh : ghat1,
                    gin_w, gin_b, gh_w, gh_b, cx1, h1, s, s == 0 };
        GJob g2 = { gi2, (s == 1) ? bh + 256 : ghat2,
                    gin_w + 256, gin_b + 256, gh_w + 256, gh_b + 256,
                    cx2, h2, s - 1, s == 1 };
        if (s == 0)
            gates_step_kernel<<<dim3(256, 1), 256, 0, stream>>>(g1, g1);
        else if (s <= 6)
            gates_step_kernel<<<dim3(256, 2), 256, 0, stream>>>(g1, g2);
        else
            gates_step_kernel<<<dim3(256, 1), 256, 0, stream>>>(g2, g2);

        // ---- convs: in1(s+1), rec1(s), in2(s), rec2(s) ----
        MJobs js{}; int nj = 0;
        if (s <= 5) js.j[nj++] = { h1 + (size_t)(s+1)*XSP, win0, bin_,     gi1 };
        if (s <= 5) js.j[nj++] = { h1 + (size_t)s*XSP,     wh0,  bh,       ghat1 };
        if (s <= 6) js.j[nj++] = { h1 + (size_t)s*XSP,     win1, bin_+256, gi2 };
        if (s >= 1 && s <= 6)
                    js.j[nj++] = { h2 + (size_t)(s-1)*XSP, wh1,  bh+256,   ghat2 };
        if (nj > 0)
            conv_mfma_kernel<<<dim3(64, nj), 256, 0, stream>>>(js);
    }

    head_kernel<<<768, 256, 0, stream>>>(h2, w1, b1, ln_g, ln_b, w2, b2, ncode, out);
}